// Round 1
// baseline (248.976 us; speedup 1.0000x reference)
//
#include <hip/hip_runtime.h>
#include <stdint.h>

#define DEV __device__ __forceinline__

typedef __attribute__((ext_vector_type(8))) unsigned short frag8;    // 8 bf16 = 4 VGPR
typedef __attribute__((ext_vector_type(4))) float f32x4;
typedef __attribute__((ext_vector_type(8))) unsigned short ushort8;
typedef __attribute__((ext_vector_type(4))) unsigned short ushort4v;

DEV unsigned short f2bf(float f) {
  union { float f; unsigned u; } x; x.f = f;
  unsigned r = x.u + 0x7fffu + ((x.u >> 16) & 1u);   // RNE
  return (unsigned short)(r >> 16);
}
DEV float bf2f(unsigned short b) {
  union { unsigned u; float f; } x; x.u = ((unsigned)b) << 16;
  return x.f;
}

DEV void gload_lds16(const void* g, void* l) {
  __builtin_amdgcn_global_load_lds((const __attribute__((address_space(1))) void*)g,
                                   (__attribute__((address_space(3))) void*)l, 16, 0, 0);
}

// D = A*B + D ; inline asm sidesteps builtin prototype differences (HK-proven)
DEV void mfma_bf16(f32x4& c, frag8 a, frag8 b) {
  asm("v_mfma_f32_16x16x32_bf16 %0, %1, %2, %0" : "+v"(c) : "v"(a), "v"(b));
}

// ---------------------------------------------------------------------------
// C[M,N] = A[M,K] * B[N,K]^T  (bf16 in, f32 acc), optional scale/bias, output
// f32 or bf16, optionally transposed (C[n,m]).  128x128 tile, BK=64, 4 waves.
// LDS XOR-swizzle (byte ^= (row&7)<<4) applied via pre-swizzled global source
// (global_load_lds writes linearly) + swizzled ds_read (rule #21).
// ---------------------------------------------------------------------------
template<int BIAS, int SCALEF, int TRANS, int F32OUT>
__global__ __launch_bounds__(256)
void gemm_bt(const unsigned short* __restrict__ A,
             const unsigned short* __restrict__ Bm,
             const float* __restrict__ bias,
             void* __restrict__ Cv,
             int M, int N, int K, float scale,
             long sA, long sB, long sC)
{
  __shared__ unsigned short ldsA[128 * 64];
  __shared__ unsigned short ldsB[128 * 64];

  const int tid  = threadIdx.x;
  const int lane = tid & 63;
  const int wave = tid >> 6;
  const int wm   = wave >> 1;           // 2x2 waves, 64x64 each
  const int wn   = wave & 1;

  const int bm = blockIdx.y * 128;
  const int bn = blockIdx.x * 128;
  const int bz = blockIdx.z;

  A  += (size_t)bz * (size_t)sA;
  Bm += (size_t)bz * (size_t)sB;

  // ---- staging addresses (per wave: 4 instrs of 1KB = 8 rows each) ----
  const int r8  = lane >> 3;            // row-within-8 (== row&7 of LDS row)
  const int l8  = lane & 7;             // 16B chunk within 128B row
  const int swz = ((l8 ^ r8) << 4);     // pre-swizzled global byte column
  const size_t Kb = (size_t)K * 2;

  const char* gA = (const char*)A  + (size_t)(bm + wave * 32 + r8) * Kb + swz;
  const char* gB = (const char*)Bm + (size_t)(bn + wave * 32 + r8) * Kb + swz;
  char* lA = (char*)ldsA + wave * 32 * 128;
  char* lB = (char*)ldsB + wave * 32 * 128;

  // ---- fragment read addresses ----
  const int cr = lane & 15;             // A-row / B-col within fragment
  const int kq = lane >> 4;             // which 8-element K chunk
  const int base16 = ((kq ^ (cr & 7)) << 4);   // swizzled byte col, kk=0
  const char* rowA = (const char*)ldsA + (wm * 64 + cr) * 128;
  const char* rowB = (const char*)ldsB + (wn * 64 + cr) * 128;

  f32x4 acc[4][4];
  #pragma unroll
  for (int m = 0; m < 4; ++m)
    #pragma unroll
    for (int n = 0; n < 4; ++n)
      acc[m][n] = f32x4{0.f, 0.f, 0.f, 0.f};

  const int nk = K >> 6;
  for (int kt = 0; kt < nk; ++kt) {
    __syncthreads();                    // LDS free of previous iter's readers
    #pragma unroll
    for (int i = 0; i < 4; ++i) {
      gload_lds16(gA + (size_t)(i * 8) * Kb, lA + i * 1024);
      gload_lds16(gB + (size_t)(i * 8) * Kb, lB + i * 1024);
    }
    __syncthreads();                    // drains vmcnt(0): tiles resident
    gA += 128; gB += 128;

    #pragma unroll
    for (int kk = 0; kk < 2; ++kk) {
      const int off = base16 ^ (kk << 6);
      frag8 a[4], b[4];
      #pragma unroll
      for (int f = 0; f < 4; ++f) {
        a[f] = *(const frag8*)(rowA + f * 2048 + off);
        b[f] = *(const frag8*)(rowB + f * 2048 + off);
      }
      #pragma unroll
      for (int m = 0; m < 4; ++m)
        #pragma unroll
        for (int n = 0; n < 4; ++n)
          mfma_bf16(acc[m][n], a[m], b[n]);
    }
  }

  // ---- epilogue: C/D layout col=lane&15, row=(lane>>4)*4+i (m89-verified) --
  #pragma unroll
  for (int m = 0; m < 4; ++m) {
    const int gr0 = bm + wm * 64 + m * 16 + kq * 4;
    #pragma unroll
    for (int n = 0; n < 4; ++n) {
      const int gc = bn + wn * 64 + n * 16 + cr;
      float bb = 0.f;
      if constexpr (BIAS) bb = bias[gc];
      float v0 = acc[m][n][0], v1 = acc[m][n][1], v2 = acc[m][n][2], v3 = acc[m][n][3];
      if constexpr (SCALEF) { v0 *= scale; v1 *= scale; v2 *= scale; v3 *= scale; }
      v0 += bb; v1 += bb; v2 += bb; v3 += bb;
      if constexpr (F32OUT) {
        float* C = (float*)Cv + (size_t)bz * (size_t)sC;
        C[(size_t)(gr0 + 0) * N + gc] = v0;
        C[(size_t)(gr0 + 1) * N + gc] = v1;
        C[(size_t)(gr0 + 2) * N + gc] = v2;
        C[(size_t)(gr0 + 3) * N + gc] = v3;
      } else if constexpr (TRANS) {
        unsigned short* C = (unsigned short*)Cv + (size_t)bz * (size_t)sC;
        ushort4v u;
        u[0] = f2bf(v0); u[1] = f2bf(v1); u[2] = f2bf(v2); u[3] = f2bf(v3);
        *(ushort4v*)&C[(size_t)gc * M + gr0] = u;   // C[n][m], 4 contiguous
      } else {
        unsigned short* C = (unsigned short*)Cv + (size_t)bz * (size_t)sC;
        C[(size_t)(gr0 + 0) * N + gc] = f2bf(v0);
        C[(size_t)(gr0 + 1) * N + gc] = f2bf(v1);
        C[(size_t)(gr0 + 2) * N + gc] = f2bf(v2);
        C[(size_t)(gr0 + 3) * N + gc] = f2bf(v3);
      }
    }
  }
}

// ---------------------------------------------------------------------------
// In-place row softmax over bf16 rows of length S=2048 (256 thr x 8 elems)
// ---------------------------------------------------------------------------
__global__ __launch_bounds__(256)
void softmax_rows(unsigned short* __restrict__ P, int S)
{
  const int tid = threadIdx.x;
  unsigned short* pr = P + (size_t)blockIdx.x * S;

  ushort8 u = *(const ushort8*)(pr + tid * 8);
  float v[8];
  float mx = -1e30f;
  #pragma unroll
  for (int j = 0; j < 8; ++j) { v[j] = bf2f(u[j]); mx = fmaxf(mx, v[j]); }

  #pragma unroll
  for (int off = 32; off; off >>= 1) mx = fmaxf(mx, __shfl_xor(mx, off));

  __shared__ float red[8];
  const int wid = tid >> 6;
  if ((tid & 63) == 0) red[wid] = mx;
  __syncthreads();
  mx = fmaxf(fmaxf(red[0], red[1]), fmaxf(red[2], red[3]));

  float e[8], s = 0.f;
  #pragma unroll
  for (int j = 0; j < 8; ++j) { e[j] = __expf(v[j] - mx); s += e[j]; }
  #pragma unroll
  for (int off = 32; off; off >>= 1) s += __shfl_xor(s, off);
  if ((tid & 63) == 0) red[4 + wid] = s;
  __syncthreads();
  s = red[4] + red[5] + red[6] + red[7];

  const float inv = 1.f / s;
  ushort8 o;
  #pragma unroll
  for (int j = 0; j < 8; ++j) o[j] = f2bf(e[j] * inv);
  *(ushort8*)(pr + tid * 8) = o;
}

// ---------------------------------------------------------------------------
// f32 -> bf16 (vectorized, n8 = n/8 groups)
// ---------------------------------------------------------------------------
__global__ __launch_bounds__(256)
void cvt_bf16(const float* __restrict__ in, unsigned short* __restrict__ out, int n8)
{
  int i = blockIdx.x * blockDim.x + threadIdx.x;
  const int stride = gridDim.x * blockDim.x;
  for (; i < n8; i += stride) {
    const float4* p = (const float4*)in + (size_t)i * 2;
    float4 a = p[0], b = p[1];
    ushort8 o;
    o[0] = f2bf(a.x); o[1] = f2bf(a.y); o[2] = f2bf(a.z); o[3] = f2bf(a.w);
    o[4] = f2bf(b.x); o[5] = f2bf(b.y); o[6] = f2bf(b.z); o[7] = f2bf(b.w);
    *((ushort8*)out + i) = o;
  }
}

// ---------------------------------------------------------------------------
// W_eff[j,d] = sum_h Wl[j, h*1024 + d]  -> bf16 [1024,1024]
// ---------------------------------------------------------------------------
__global__ __launch_bounds__(256)
void weff_kernel(const float* __restrict__ Wl, unsigned short* __restrict__ out)
{
  const int idx = blockIdx.x * 256 + threadIdx.x;   // 0 .. 262143
  const int j = idx >> 8;
  const int d = (idx & 255) << 2;
  float4 s = make_float4(0.f, 0.f, 0.f, 0.f);
  #pragma unroll
  for (int h = 0; h < 8; ++h) {
    float4 w = *(const float4*)&Wl[(size_t)j * 8192 + h * 1024 + d];
    s.x += w.x; s.y += w.y; s.z += w.z; s.w += w.w;
  }
  ushort4v o;
  o[0] = f2bf(s.x); o[1] = f2bf(s.y); o[2] = f2bf(s.z); o[3] = f2bf(s.w);
  *(ushort4v*)&out[(size_t)j * 1024 + d] = o;
}

// ---------------------------------------------------------------------------
extern "C" void kernel_launch(void* const* d_in, const int* in_sizes, int n_in,
                              void* d_out, int out_size, void* d_ws, size_t ws_size,
                              hipStream_t stream)
{
  (void)in_sizes; (void)n_in; (void)out_size; (void)ws_size;

  const float* Q  = (const float*)d_in[0];
  const float* K  = (const float*)d_in[1];
  const float* V  = (const float*)d_in[2];
  const float* WQ = (const float*)d_in[3];
  const float* bQ = (const float*)d_in[4];
  const float* WK = (const float*)d_in[5];
  const float* bK = (const float*)d_in[6];
  const float* WV = (const float*)d_in[7];
  const float* bV = (const float*)d_in[8];
  const float* Wl = (const float*)d_in[9];
  const float* bl = (const float*)d_in[10];

  const size_t nX = (size_t)8192 * 1024;   // B*S*D
  const size_t nW = (size_t)1024 * 1024;

  // workspace layout (bf16 elements); P overlays Qb+Kb, Z overlays Vb
  unsigned short* Qb  = (unsigned short*)d_ws;
  unsigned short* Kb  = Qb + nX;
  unsigned short* Vb  = Kb + nX;
  unsigned short* qb  = Vb + nX;
  unsigned short* kb  = qb + nX;
  unsigned short* vT  = kb + nX;          // [B][D][S]
  unsigned short* Wqb = vT + nX;
  unsigned short* Wkb = Wqb + nW;
  unsigned short* Wvb = Wkb + nW;
  unsigned short* Wef = Wvb + nW;
  unsigned short* P   = Qb;               // [B][S][S] = 2*nX, reuses Qb+Kb
  unsigned short* Zb  = Vb;               // [B*S][D], reuses Vb

  const int thr = 256;

  cvt_bf16<<<4096, thr, 0, stream>>>(Q, Qb, (int)(nX / 8));
  cvt_bf16<<<4096, thr, 0, stream>>>(K, Kb, (int)(nX / 8));
  cvt_bf16<<<4096, thr, 0, stream>>>(V, Vb, (int)(nX / 8));
  cvt_bf16<<<512,  thr, 0, stream>>>(WQ, Wqb, (int)(nW / 8));
  cvt_bf16<<<512,  thr, 0, stream>>>(WK, Wkb, (int)(nW / 8));
  cvt_bf16<<<512,  thr, 0, stream>>>(WV, Wvb, (int)(nW / 8));
  weff_kernel<<<1024, thr, 0, stream>>>(Wl, Wef);

  // q = Qb*WQ^T + bQ     [8192,1024]
  gemm_bt<1,0,0,0><<<dim3(8, 64, 1), thr, 0, stream>>>(
      Qb, Wqb, bQ, qb, 8192, 1024, 1024, 1.f, 0, 0, 0);
  // k = Kb*WK^T + bK
  gemm_bt<1,0,0,0><<<dim3(8, 64, 1), thr, 0, stream>>>(
      Kb, Wkb, bK, kb, 8192, 1024, 1024, 1.f, 0, 0, 0);
  // vT[b][d][s] = (Vb*WV^T + bV)^T, batched (weights shared: sB=0)
  gemm_bt<1,0,1,0><<<dim3(8, 16, 4), thr, 0, stream>>>(
      Vb, Wvb, bV, vT, 2048, 1024, 1024, 1.f,
      (long)2048 * 1024, 0, (long)1024 * 2048);
  // scores = q*k^T / 32  [b][2048][2048]
  gemm_bt<0,1,0,0><<<dim3(16, 16, 4), thr, 0, stream>>>(
      qb, kb, nullptr, P, 2048, 2048, 1024, 0.03125f,
      (long)2048 * 1024, (long)2048 * 1024, (long)2048 * 2048);
  // softmax rows in place
  softmax_rows<<<8192, thr, 0, stream>>>(P, 2048);
  // Z = P * vT^T  (bt-GEMM: sum_j P[i,j] * vT[d,j])
  gemm_bt<0,0,0,0><<<dim3(8, 16, 4), thr, 0, stream>>>(
      P, vT, nullptr, Zb, 2048, 1024, 2048, 1.f,
      (long)2048 * 2048, (long)1024 * 2048, (long)2048 * 1024);
  // out = Z * Weff^T + bl  -> f32
  gemm_bt<1,0,0,1><<<dim3(8, 64, 1), thr, 0, stream>>>(
      Zb, Wef, bl, d_out, 8192, 1024, 1024, 1.f, 0, 0, 0);
}

// Round 2
// 212.759 us; speedup vs baseline: 1.1702x; 1.1702x over previous
//
#include <hip/hip_runtime.h>
#include <stdint.h>

#define DEV __device__ __forceinline__

typedef __attribute__((ext_vector_type(8))) unsigned short frag8;    // 8 bf16 = 4 VGPR
typedef __attribute__((ext_vector_type(4))) float f32x4;
typedef __attribute__((ext_vector_type(8))) unsigned short ushort8;
typedef __attribute__((ext_vector_type(4))) unsigned short ushort4v;

DEV unsigned short f2bf(float f) {
  union { float f; unsigned u; } x; x.f = f;
  unsigned r = x.u + 0x7fffu + ((x.u >> 16) & 1u);   // RNE
  return (unsigned short)(r >> 16);
}
DEV float bf2f(unsigned short b) {
  union { unsigned u; float f; } x; x.u = ((unsigned)b) << 16;
  return x.f;
}

DEV void gload_lds16(const void* g, void* l) {
  __builtin_amdgcn_global_load_lds((const __attribute__((address_space(1))) void*)g,
                                   (__attribute__((address_space(3))) void*)l, 16, 0, 0);
}

DEV void mfma_bf16(f32x4& c, frag8 a, frag8 b) {
  asm("v_mfma_f32_16x16x32_bf16 %0, %1, %2, %0" : "+v"(c) : "v"(a), "v"(b));
}

// raw barrier with counted wait: drain our stage loads, sync, and fence the
// compiler so LDS reads can't hoist above the barrier (rule #18 analog).
DEV void wait_vm0_barrier() {
  asm volatile("s_waitcnt vmcnt(0)" ::: "memory");
  __builtin_amdgcn_s_barrier();
  asm volatile("" ::: "memory");
  __builtin_amdgcn_sched_barrier(0);
}

// ---------------------------------------------------------------------------
// C[M,N] = A[M,K]*B[N,K]^T, bf16 in / f32 acc. 128x128 tile, BK=64, 4 waves,
// double-buffered LDS with T3-minimum 2-phase prefetch (stage t+1 before
// computing t; one vmcnt(0)+raw-barrier per K-step). XOR-swizzled LDS via
// pre-swizzled global source (rule #21). 1D grid + bijective XCD swizzle (T1).
// MODE: 0 = bf16 out, 1 = f32 out, 2 = fused projections (bz<2 normal bf16,
//       bz==2 writes transposed into vT at Cv + 2*sC; bias selected by bz).
// ---------------------------------------------------------------------------
template<int BIAS, int SCALEF, int MODE>
__global__ __launch_bounds__(256)
void gemm_bt(const unsigned short* __restrict__ A,
             const unsigned short* __restrict__ Bm,
             const float* __restrict__ bias0, const float* __restrict__ bias1,
             const float* __restrict__ bias2,
             void* __restrict__ Cv,
             int N, int K, float scale,
             long sA, long sB, long sC,
             int nx, int ny)
{
  __shared__ unsigned short lds[2][2][128 * 64];   // [buf][A/B], 64 KiB

  const int tid  = threadIdx.x;
  const int lane = tid & 63;
  const int wave = tid >> 6;
  const int wm   = wave >> 1;           // 2x2 waves, 64x64 each
  const int wn   = wave & 1;

  // ---- bijective XCD swizzle (m204) + grid decomposition ----
  const unsigned nwg = gridDim.x;
  const unsigned orig = blockIdx.x;
  const unsigned qq = nwg >> 3, rr = nwg & 7;
  const unsigned xcd = orig & 7, jj = orig >> 3;
  const unsigned wg = (xcd < rr ? xcd * (qq + 1) : rr * (qq + 1) + (xcd - rr) * qq) + jj;
  const unsigned bx = wg % (unsigned)nx;
  const unsigned tt = wg / (unsigned)nx;
  const unsigned by = tt % (unsigned)ny;
  const unsigned bz = tt / (unsigned)ny;

  const int bm = (int)by * 128;
  const int bn = (int)bx * 128;

  A  += (size_t)bz * (size_t)sA;
  Bm += (size_t)bz * (size_t)sB;

  // ---- staging addresses (per wave: 4 instrs of 1KB = 8 rows each side) ----
  const int r8  = lane >> 3;
  const int l8  = lane & 7;
  const int swz = ((l8 ^ r8) << 4);     // pre-swizzled global byte column
  const size_t Kb = (size_t)K * 2;

  const char* gA = (const char*)A  + (size_t)(bm + wave * 32 + r8) * Kb + swz;
  const char* gB = (const char*)Bm + (size_t)(bn + wave * 32 + r8) * Kb + swz;
  char* lA0 = (char*)&lds[0][0][0] + wave * 32 * 128;
  char* lB0 = (char*)&lds[0][1][0] + wave * 32 * 128;
  char* lA1 = (char*)&lds[1][0][0] + wave * 32 * 128;
  char* lB1 = (char*)&lds[1][1][0] + wave * 32 * 128;

  // ---- fragment read addresses ----
  const int cr = lane & 15;
  const int kq = lane >> 4;
  const int base16 = ((kq ^ (cr & 7)) << 4);
  const char* rA0 = (const char*)&lds[0][0][0] + (wm * 64 + cr) * 128;
  const char* rB0 = (const char*)&lds[0][1][0] + (wn * 64 + cr) * 128;
  const char* rA1 = (const char*)&lds[1][0][0] + (wm * 64 + cr) * 128;
  const char* rB1 = (const char*)&lds[1][1][0] + (wn * 64 + cr) * 128;

  f32x4 acc[4][4];
  #pragma unroll
  for (int m = 0; m < 4; ++m)
    #pragma unroll
    for (int n = 0; n < 4; ++n)
      acc[m][n] = f32x4{0.f, 0.f, 0.f, 0.f};

  auto STAGE = [&](int t, char* la, char* lb) {
    const char* ga = gA + (size_t)t * 128;
    const char* gb = gB + (size_t)t * 128;
    gload_lds16(ga,               la);
    gload_lds16(gb,               lb);
    gload_lds16(ga +  8 * Kb,     la + 1024);
    gload_lds16(gb +  8 * Kb,     lb + 1024);
    gload_lds16(ga + 16 * Kb,     la + 2048);
    gload_lds16(gb + 16 * Kb,     lb + 2048);
    gload_lds16(ga + 24 * Kb,     la + 3072);
    gload_lds16(gb + 24 * Kb,     lb + 3072);
  };
  auto COMPUTE = [&](const char* ra, const char* rb) {
    #pragma unroll
    for (int kk = 0; kk < 2; ++kk) {
      const int off = base16 ^ (kk << 6);
      frag8 a[4], b[4];
      #pragma unroll
      for (int f = 0; f < 4; ++f) {
        a[f] = *(const frag8*)(ra + f * 2048 + off);
        b[f] = *(const frag8*)(rb + f * 2048 + off);
      }
      #pragma unroll
      for (int m = 0; m < 4; ++m)
        #pragma unroll
        for (int n = 0; n < 4; ++n)
          mfma_bf16(acc[m][n], a[m], b[n]);
    }
  };

  const int nk = K >> 6;                // K = 1024/2048 -> nk even
  STAGE(0, lA0, lB0);
  wait_vm0_barrier();
  for (int kt = 0; kt < nk; kt += 2) {
    STAGE(kt + 1, lA1, lB1);            // kt+1 < nk always (nk even)
    COMPUTE(rA0, rB0);
    wait_vm0_barrier();
    if (kt + 2 < nk) STAGE(kt + 2, lA0, lB0);
    COMPUTE(rA1, rB1);
    wait_vm0_barrier();
  }

  // ---- epilogue: C/D layout col=lane&15, row=(lane>>4)*4+i (m89-verified) --
  const float* bias = bias0;
  if constexpr (MODE == 2) bias = (bz == 0) ? bias0 : (bz == 1) ? bias1 : bias2;

  #pragma unroll
  for (int m = 0; m < 4; ++m) {
    const int gr0 = bm + wm * 64 + m * 16 + kq * 4;
    #pragma unroll
    for (int n = 0; n < 4; ++n) {
      const int gc = bn + wn * 64 + n * 16 + cr;
      float bb = 0.f;
      if constexpr (BIAS) bb = bias[gc];
      float v0 = acc[m][n][0], v1 = acc[m][n][1], v2 = acc[m][n][2], v3 = acc[m][n][3];
      if constexpr (SCALEF) { v0 *= scale; v1 *= scale; v2 *= scale; v3 *= scale; }
      v0 += bb; v1 += bb; v2 += bb; v3 += bb;
      if constexpr (MODE == 1) {
        float* C = (float*)Cv + (size_t)bz * (size_t)sC;
        C[(size_t)(gr0 + 0) * N + gc] = v0;
        C[(size_t)(gr0 + 1) * N + gc] = v1;
        C[(size_t)(gr0 + 2) * N + gc] = v2;
        C[(size_t)(gr0 + 3) * N + gc] = v3;
      } else if constexpr (MODE == 2) {
        if (bz == 2) {
          // transposed store into vT[b][d][s], b = gr0>>11, s = gr0&2047
          unsigned short* C = (unsigned short*)Cv + (size_t)2 * (size_t)sC;
          ushort4v u;
          u[0] = f2bf(v0); u[1] = f2bf(v1); u[2] = f2bf(v2); u[3] = f2bf(v3);
          *(ushort4v*)&C[((size_t)(gr0 >> 11) << 21) + (size_t)gc * 2048 + (gr0 & 2047)] = u;
        } else {
          unsigned short* C = (unsigned short*)Cv + (size_t)bz * (size_t)sC;
          C[(size_t)(gr0 + 0) * N + gc] = f2bf(v0);
          C[(size_t)(gr0 + 1) * N + gc] = f2bf(v1);
          C[(size_t)(gr0 + 2) * N + gc] = f2bf(v2);
          C[(size_t)(gr0 + 3) * N + gc] = f2bf(v3);
        }
      } else {
        unsigned short* C = (unsigned short*)Cv + (size_t)bz * (size_t)sC;
        C[(size_t)(gr0 + 0) * N + gc] = f2bf(v0);
        C[(size_t)(gr0 + 1) * N + gc] = f2bf(v1);
        C[(size_t)(gr0 + 2) * N + gc] = f2bf(v2);
        C[(size_t)(gr0 + 3) * N + gc] = f2bf(v3);
      }
    }
  }
}

// ---------------------------------------------------------------------------
// In-place row softmax over bf16 rows of length S=2048 (256 thr x 8 elems)
// ---------------------------------------------------------------------------
__global__ __launch_bounds__(256)
void softmax_rows(unsigned short* __restrict__ P, int S)
{
  const int tid = threadIdx.x;
  unsigned short* pr = P + (size_t)blockIdx.x * S;

  ushort8 u = *(const ushort8*)(pr + tid * 8);
  float v[8];
  float mx = -1e30f;
  #pragma unroll
  for (int j = 0; j < 8; ++j) { v[j] = bf2f(u[j]); mx = fmaxf(mx, v[j]); }

  #pragma unroll
  for (int off = 32; off; off >>= 1) mx = fmaxf(mx, __shfl_xor(mx, off));

  __shared__ float red[8];
  const int wid = tid >> 6;
  if ((tid & 63) == 0) red[wid] = mx;
  __syncthreads();
  mx = fmaxf(fmaxf(red[0], red[1]), fmaxf(red[2], red[3]));

  float e[8], s = 0.f;
  #pragma unroll
  for (int j = 0; j < 8; ++j) { e[j] = __expf(v[j] - mx); s += e[j]; }
  #pragma unroll
  for (int off = 32; off; off >>= 1) s += __shfl_xor(s, off);
  if ((tid & 63) == 0) red[4 + wid] = s;
  __syncthreads();
  s = red[4] + red[5] + red[6] + red[7];

  const float inv = 1.f / s;
  ushort8 o;
  #pragma unroll
  for (int j = 0; j < 8; ++j) o[j] = f2bf(e[j] * inv);
  *(ushort8*)(pr + tid * 8) = o;
}

// ---------------------------------------------------------------------------
// fused f32 -> bf16 for three equal-size tensors (blockIdx.y selects)
// ---------------------------------------------------------------------------
__global__ __launch_bounds__(256)
void cvt3_bf16(const float* __restrict__ s0, const float* __restrict__ s1,
               const float* __restrict__ s2, unsigned short* __restrict__ out,
               int n8each)
{
  const float* src = (blockIdx.y == 0) ? s0 : (blockIdx.y == 1) ? s1 : s2;
  unsigned short* dst = out + (size_t)blockIdx.y * ((size_t)n8each * 8);
  int i = blockIdx.x * blockDim.x + threadIdx.x;
  const int stride = gridDim.x * blockDim.x;
  for (; i < n8each; i += stride) {
    const float4* p = (const float4*)src + (size_t)i * 2;
    float4 a = p[0], b = p[1];
    ushort8 o;
    o[0] = f2bf(a.x); o[1] = f2bf(a.y); o[2] = f2bf(a.z); o[3] = f2bf(a.w);
    o[4] = f2bf(b.x); o[5] = f2bf(b.y); o[6] = f2bf(b.z); o[7] = f2bf(b.w);
    *((ushort8*)dst + i) = o;
  }
}

// ---------------------------------------------------------------------------
// W_eff[j,d] = sum_h Wl[j, h*1024 + d]  -> bf16 [1024,1024]
// ---------------------------------------------------------------------------
__global__ __launch_bounds__(256)
void weff_kernel(const float* __restrict__ Wl, unsigned short* __restrict__ out)
{
  const int idx = blockIdx.x * 256 + threadIdx.x;   // 0 .. 262143
  const int j = idx >> 8;
  const int d = (idx & 255) << 2;
  float4 s = make_float4(0.f, 0.f, 0.f, 0.f);
  #pragma unroll
  for (int h = 0; h < 8; ++h) {
    float4 w = *(const float4*)&Wl[(size_t)j * 8192 + h * 1024 + d];
    s.x += w.x; s.y += w.y; s.z += w.z; s.w += w.w;
  }
  ushort4v o;
  o[0] = f2bf(s.x); o[1] = f2bf(s.y); o[2] = f2bf(s.z); o[3] = f2bf(s.w);
  *(ushort4v*)&out[(size_t)j * 1024 + d] = o;
}

// ---------------------------------------------------------------------------
extern "C" void kernel_launch(void* const* d_in, const int* in_sizes, int n_in,
                              void* d_out, int out_size, void* d_ws, size_t ws_size,
                              hipStream_t stream)
{
  (void)in_sizes; (void)n_in; (void)out_size; (void)ws_size;

  const float* Q  = (const float*)d_in[0];
  const float* K  = (const float*)d_in[1];
  const float* V  = (const float*)d_in[2];
  const float* WQ = (const float*)d_in[3];
  const float* bQ = (const float*)d_in[4];
  const float* WK = (const float*)d_in[5];
  const float* bK = (const float*)d_in[6];
  const float* WV = (const float*)d_in[7];
  const float* bV = (const float*)d_in[8];
  const float* Wl = (const float*)d_in[9];
  const float* bl = (const float*)d_in[10];

  const size_t nX = (size_t)8192 * 1024;   // B*S*D
  const size_t nW = (size_t)1024 * 1024;

  // workspace layout (bf16 elements); P overlays Qb+Kb, Z overlays Vb
  unsigned short* Qb  = (unsigned short*)d_ws;   // Qb,Kb,Vb contiguous
  unsigned short* Vb  = Qb + 2 * nX;
  unsigned short* qb  = Vb + nX;                 // qb,kb,vT contiguous
  unsigned short* vT  = qb + 2 * nX;             // [B][D][S]
  unsigned short* Wqb = vT + nX;                 // Wqb,Wkb,Wvb contiguous
  unsigned short* Wef = Wqb + 3 * nW;
  unsigned short* P   = Qb;                      // [B][S][S] = 2*nX
  unsigned short* kb  = qb + nX;
  unsigned short* Zb  = Vb;                      // [B*S][D]

  const int thr = 256;

  cvt3_bf16<<<dim3(1024, 3), thr, 0, stream>>>(Q, K, V, Qb, (int)(nX / 8));
  cvt3_bf16<<<dim3(512, 3),  thr, 0, stream>>>(WQ, WK, WV, Wqb, (int)(nW / 8));
  weff_kernel<<<1024, thr, 0, stream>>>(Wl, Wef);

  // fused projections: z=0 -> qb, z=1 -> kb, z=2 -> vT (transposed)
  gemm_bt<1, 0, 2><<<1536, thr, 0, stream>>>(
      Qb, Wqb, bQ, bK, bV, qb, 1024, 1024, 1.f,
      (long)nX, (long)nW, (long)nX, 8, 64);
  // scores = q*k^T / 32   [b][2048][2048]
  gemm_bt<0, 1, 0><<<1024, thr, 0, stream>>>(
      qb, kb, nullptr, nullptr, nullptr, P, 2048, 1024, 0.03125f,
      (long)(2048 * 1024), (long)(2048 * 1024), (long)(2048 * 2048), 16, 16);
  softmax_rows<<<8192, thr, 0, stream>>>(P, 2048);
  // Z = P * vT^T
  gemm_bt<0, 0, 0><<<512, thr, 0, stream>>>(
      P, vT, nullptr, nullptr, nullptr, Zb, 1024, 2048, 1.f,
      (long)(2048 * 2048), (long)(1024 * 2048), (long)(2048 * 1024), 8, 16);
  // out = Z * Weff^T + bl  -> f32
  gemm_bt<1, 0, 1><<<512, thr, 0, stream>>>(
      Zb, Wef, bl, nullptr, nullptr, d_out, 1024, 1024, 1.f,
      0, 0, 0, 8, 64);
}